// Round 12
// baseline (141.534 us; speedup 1.0000x reference)
//
#include <hip/hip_runtime.h>

// LSS view transform, chunked-gather formulation, sharded + wave-run binning.
// out[b,c,cell] = sum_{(pix,d)->cell} img[b,c,pix] * dp[b,d,pix]
// Round-20 (base = round-11, 141.0us; R11 exposed gather = 51us cold, 36% of
// total, latency-bound: VALUBusy 13%, HBM 7.7%, VGPR only 24).
//  - k_chunk_gather: 2-deep group-of-8 pipeline -> load ALL 64 rows first
//    (4 x 16 named reg arrays, compile-time indices), then accumulate.
//    Outstanding VMEM/wave 8-16 -> ~63 (vmcnt cap). Accumulation order over
//    entries 0..63 unchanged -> bit-identical output.
//  - everything else byte-identical to round 11.
constexpr int IMG_H = 48, IMG_W = 160;
constexpr int HW    = IMG_H * IMG_W;          // 7680
constexpr int BEV_H = 128, BEV_W = 128;
constexpr int NCELL = BEV_H * BEV_W;          // 16384 per batch
constexpr int C_DIM = 128, D_DIM = 64, B_DIM = 2;
constexpr int NCELL_TOT = B_DIM * NCELL;      // 32768
constexpr int NPIX_TOT  = B_DIM * HW;         // 15360
constexpr int NPTS      = NPIX_TOT * D_DIM;   // 983040
constexpr int MAX_ENTRIES = NPTS;
constexpr int CHUNK = 64;
constexpr int WAVES_PER_BLK = 4;
constexpr int NSHARD = 16;
constexpr int CNT_BLOCKS = NPTS / 256;        // 3840
constexpr int TRN_BLOCKS = (HW / 32) * (C_DIM / 32) * B_DIM;  // 1920
constexpr int PREP_TOTAL = CNT_BLOCKS + TRN_BLOCKS;           // 5760
constexpr int SCAN_BLOCKS = NCELL_TOT / 256;  // 128
constexpr float X_MIN = -51.2f, Y_MIN = -51.2f;
constexpr float RES_X = 102.4f / 128.0f;
constexpr float RES_Y = 102.4f / 128.0f;

typedef _Float16 half2v __attribute__((ext_vector_type(2)));

// ---- ws layout (4-byte words), ~28.8 MB total ----
constexpr size_t WS_IMG_T = 0;                                      // half[B*HW*C]
constexpr size_t WS_TOT   = WS_IMG_T + (size_t)B_DIM * HW * C_DIM / 2;  // int[4] [memset]
constexpr size_t WS_HIST2 = WS_TOT + 4;                             // int[16*32768] [memset, adjacent]
constexpr size_t WS_OUT_T = WS_HIST2 + (size_t)NSHARD * NCELL_TOT;  // float[32768*128] (zeroed by prep)
constexpr size_t WS_OFFS  = WS_OUT_T + (size_t)NCELL_TOT * C_DIM;   // int[32769]+pad
constexpr size_t WS_EKEY  = WS_OFFS + NCELL_TOT + 4;                // int[NPTS]
constexpr size_t WS_EW16  = WS_EKEY + MAX_ENTRIES;                  // ushort[NPTS]
constexpr size_t MEMSET_WORDS = 4 + (size_t)NSHARD * NCELL_TOT;     // ~2.1 MB
constexpr int OUT_T_F4 = NCELL_TOT * C_DIM / 4;                     // 1048576 float4s

__device__ inline int point_shard(int tid) {
    return ((tid >> 2) + (tid >> 8)) & (NSHARD - 1);   // deterministic in tid
}

__device__ inline void make_ray(const float* __restrict__ K, int b, float gx, float gy,
                                float& rx, float& ry, float& rz) {
    const float* Kb = K + b * 9;
    const float a00 = Kb[0], a01 = Kb[1], a02 = Kb[2];
    const float a10 = Kb[3], a11 = Kb[4], a12 = Kb[5];
    const float a20 = Kb[6], a21 = Kb[7], a22 = Kb[8];
    const float det = a00 * (a11 * a22 - a12 * a21)
                    - a01 * (a10 * a22 - a12 * a20)
                    + a02 * (a10 * a21 - a11 * a20);
    const float inv = 1.0f / det;
    const float i00 =  (a11 * a22 - a12 * a21) * inv;
    const float i01 = -(a01 * a22 - a02 * a21) * inv;
    const float i02 =  (a01 * a12 - a02 * a11) * inv;
    const float i10 = -(a10 * a22 - a12 * a20) * inv;
    const float i11 =  (a00 * a22 - a02 * a20) * inv;
    const float i12 = -(a00 * a12 - a02 * a10) * inv;
    const float i20 =  (a10 * a21 - a11 * a20) * inv;
    const float i21 = -(a00 * a21 - a01 * a20) * inv;
    const float i22 =  (a00 * a11 - a01 * a10) * inv;
    rx = i00 * gx + i01 * gy + i02;
    ry = i10 * gx + i11 * gy + i12;
    rz = i20 * gx + i21 * gy + i22;
}

// Returns global cell id (b*NCELL + cell) or -1. tid = ((b*D + d)*HW + pix).
__device__ inline int point_gcell(int tid, const float* __restrict__ dv,
                                  const float* __restrict__ K,
                                  const float* __restrict__ T) {
    const int pix = tid % HW;
    const int bd  = tid / HW;
    const int d   = bd % D_DIM;
    const int b   = bd / D_DIM;
    const int h = pix / IMG_W, w = pix % IMG_W;
    float rx, ry, rz;
    make_ray(K, b, (float)w, (float)h, rx, ry, rz);
    const float* Tb = T + b * 16;
    const float dep = dv[d];                       // wave-uniform
    const float px = dep * rx, py = dep * ry, pz = dep * rz;
    const float x = Tb[0] * px + Tb[1] * py + Tb[2]  * pz + Tb[3];
    const float y = Tb[4] * px + Tb[5] * py + Tb[6]  * pz + Tb[7];
    const float z = Tb[8] * px + Tb[9] * py + Tb[10] * pz + Tb[11];
    const int bx = (int)((x - X_MIN) / RES_X);     // truncate-toward-zero == astype(int32)
    const int by = (int)((y - Y_MIN) / RES_Y);
    const bool valid = (bx >= 0) && (bx < BEV_W) && (by >= 0) && (by < BEV_H) && (z > 0.0f);
    return valid ? (b * NCELL + by * BEV_W + bx) : -1;
}

// Wave-run helpers: lanes are consecutive pixels -> equal-cell runs.
__device__ inline bool wave_runs(int gcell, int lane, int& run_len, int& leader_idx) {
    const int left = __shfl_up(gcell, 1);          // width 64
    const bool is_leader = (lane == 0) || (left != gcell);
    const unsigned long long lmask = __ballot(is_leader);
    const unsigned long long rest = (lane == 63) ? 0ULL : (lmask >> (lane + 1));
    const int f = __ffsll((unsigned long long)rest);   // 1+idx or 0
    run_len = f ? f : (64 - lane);
    const unsigned long long below =
        lmask & ((lane == 63) ? ~0ULL : ((1ULL << (lane + 1)) - 1ULL));
    leader_idx = 63 - __clzll((long long)below);
    return is_leader;
}

// ---- K1: fused {sharded count | transpose/fp16 | out_t zero} ----
__global__ __launch_bounds__(256) void k_prep(const float* __restrict__ img,
                                              _Float16* __restrict__ img_t,
                                              const float* __restrict__ dv,
                                              const float* __restrict__ K,
                                              const float* __restrict__ T,
                                              int* __restrict__ hist2,
                                              float4* __restrict__ out_t4) {
    __shared__ float tile[32][33];
    const int t = threadIdx.x;

    // zero out_t stripe (grid covers all of it; <=1 float4 per thread)
    {
        const int i = blockIdx.x * 256 + t;
        if (i < OUT_T_F4) out_t4[i] = make_float4(0.f, 0.f, 0.f, 0.f);
    }

    if (blockIdx.x < CNT_BLOCKS) {
        const int tid = blockIdx.x * 256 + t;             // < NPTS (exact)
        const int gcell = point_gcell(tid, dv, K, T);
        const int lane = t & 63;
        int run_len, leader_idx;
        const bool lead = wave_runs(gcell, lane, run_len, leader_idx);
        if (lead && gcell >= 0)
            atomicAdd(&hist2[(size_t)point_shard(tid) * NCELL_TOT + gcell], run_len);
    } else {
        const int bi = blockIdx.x - CNT_BLOCKS;
        const int px_t = bi % (HW / 32);
        const int c_t  = (bi / (HW / 32)) % (C_DIM / 32);
        const int b    = bi / ((HW / 32) * (C_DIM / 32));
        const int tx = t & 31, ty = t >> 5;               // (32,8)
        const int pix0 = px_t * 32, c0 = c_t * 32;
        #pragma unroll
        for (int j = 0; j < 32; j += 8)
            tile[ty + j][tx] = img[((size_t)(b * C_DIM + c0 + ty + j)) * HW + pix0 + tx];
        __syncthreads();
        #pragma unroll
        for (int j = 0; j < 32; j += 8)
            img_t[((size_t)(b * HW + pix0 + ty + j)) * C_DIM + c0 + tx] =
                (_Float16)tile[tx][ty + j];
    }
}

// ---- K2: fence-free scan. Shard-reduce + in-place local prefix; block scan;
// base claimed in ARRIVAL order via relaxed atomicAdd (entry ranges need
// disjointness, not cell order). 128th arriver publishes offs[NCELL_TOT].
__global__ __launch_bounds__(256) void k_scan(int* __restrict__ hist2,
                                              int* __restrict__ offs,
                                              int* __restrict__ tot) {
    __shared__ int lds[256];
    __shared__ int s_base;
    const int b = blockIdx.x;                      // 128 blocks
    const int t = threadIdx.x;                     // 256 threads
    const int cell = b * 256 + t;
    // shard reduce + in-place local exclusive prefix (coalesced sweeps)
    int run = 0;
    #pragma unroll
    for (int sh = 0; sh < NSHARD; ++sh) {
        const size_t idx = (size_t)sh * NCELL_TOT + cell;
        const int c = hist2[idx];
        hist2[idx] = run;          // local exclusive prefix (cursor base for fill)
        run += c;
    }
    const int h = run;                             // cell total
    // inclusive block scan
    lds[t] = h;
    __syncthreads();
    #pragma unroll
    for (int off = 1; off < 256; off <<= 1) {
        const int v = (t >= off) ? lds[t - off] : 0;
        __syncthreads();
        lds[t] += v;
        __syncthreads();
    }
    const int incl = lds[t];
    const int S = lds[255];                        // block aggregate
    if (t == 0) {
        s_base = atomicAdd(&tot[0], S);            // relaxed, arrival order
        const int arr = atomicAdd(&tot[1], 1);
        if (arr == SCAN_BLOCKS - 1)                // last arrival: all adds landed
            offs[NCELL_TOT] = atomicAdd(&tot[0], 0);   // read final total
    }
    __syncthreads();
    offs[cell] = s_base + incl - h;                // global exclusive prefix
}

// ---- K3: fill entries; leader reserves span via offs + local shard cursor ----
__global__ __launch_bounds__(256) void k_fill(const float* __restrict__ dp,
                                              const float* __restrict__ dv,
                                              const float* __restrict__ K,
                                              const float* __restrict__ T,
                                              const int* __restrict__ offs,
                                              int* __restrict__ cursor2,   // = hist2 (local prefix)
                                              int* __restrict__ ekey,
                                              unsigned short* __restrict__ ew16) {
    const int tid = blockIdx.x * 256 + threadIdx.x;   // < NPTS (exact grid)
    const int gcell = point_gcell(tid, dv, K, T);
    const int lane = threadIdx.x & 63;
    int run_len, leader_idx;
    const bool lead = wave_runs(gcell, lane, run_len, leader_idx);
    int base = 0;
    if (lead && gcell >= 0)
        base = offs[gcell]
             + atomicAdd(&cursor2[(size_t)point_shard(tid) * NCELL_TOT + gcell], run_len);
    base = __shfl(base, leader_idx);                  // broadcast my run's base
    if (gcell < 0) return;
    const int slot = base + (lane - leader_idx);      // contiguous, coalesced writes
    const float p = dp[tid];                          // tid == ((b*D+d)*HW+pix): coalesced
    ekey[slot] = (gcell << 13) | (tid % HW);
    ew16[slot] = (unsigned short)__float2uint_rn(p * 65535.0f);
}

// ---- K4: chunked segmented reduction, MAX-MLP variant. 4 waves/block,
// wave = one 64-entry chunk, thread = 2 channels. ALL 64 row loads issued
// before any accumulation (4 x 16 named reg arrays, compile-time indices)
// -> ~63 outstanding VMEM/wave (vmcnt cap) vs 8-16 in the 2-deep pipeline.
// Accumulation order over entries 0..63 identical -> bit-identical output.
__global__ __launch_bounds__(256) void k_chunk_gather(
    const _Float16* __restrict__ img_t,
    const int* __restrict__ offs,     // offs[NCELL_TOT] = total entry count
    const int* __restrict__ ekey,
    const unsigned short* __restrict__ ew16,
    float* __restrict__ out_t)
{
    const int total = offs[NCELL_TOT];
    const int wave  = threadIdx.x >> 6;
    const int lane  = threadIdx.x & 63;
    const int base  = (blockIdx.x * WAVES_PER_BLK + wave) * CHUNK;
    if (base >= total) return;

    // per-lane entry fetch (coalesced); pad = dup last key, weight 0
    const int eidx = min(base + lane, total - 1);
    const int   mykey = ekey[eidx];
    const float myw   = (base + lane < total)
                        ? (float)ew16[base + lane] * (1.0f / 65535.0f) : 0.0f;
    const int mywi = __float_as_int(myw);

    const int c2 = lane * 2;                          // channels c2, c2+1
    const int fc    = __builtin_amdgcn_readlane(mykey, 0) >> 13;   // first cell
    const int lcell = __builtin_amdgcn_readlane(mykey, 63) >> 13;  // last cell
    // boundary-continuation flags (uniform scalar loads, broadcast by cache)
    const bool shared_first = (base > 0) && ((ekey[base - 1] >> 13) == fc);
    const bool shared_last  = (base + CHUNK < total) && ((ekey[base + CHUNK] >> 13) == lcell);

    int prev = fc;
    float2 acc = make_float2(0.0f, 0.0f);

#define LOAD16(g, V)                                                             \
    do {                                                                         \
        _Pragma("unroll")                                                        \
        for (int k = 0; k < 16; ++k) {                                           \
            const int key = __builtin_amdgcn_readlane(mykey, (g) * 16 + k);      \
            const int pix = key & 8191;                                          \
            const int bb  = key >> 27;                                           \
            V[k] = *reinterpret_cast<const half2v*>(                             \
                &img_t[((size_t)(bb * HW + pix)) * C_DIM + c2]);                 \
        }                                                                        \
    } while (0)

#define FLUSHP(cell)                                                             \
    do {                                                                         \
        float* o = &out_t[(size_t)(cell) * C_DIM + c2];                          \
        const bool shared_ = ((cell) == fc && shared_first) ||                   \
                             ((cell) == lcell && shared_last);                   \
        if (shared_) {                                                           \
            atomicAdd(o, acc.x);                                                 \
            atomicAdd(o + 1, acc.y);                                             \
        } else {                                                                 \
            *reinterpret_cast<float2*>(o) = acc;  /* exclusive owner */          \
        }                                                                        \
    } while (0)

#define ACC16(g, V)                                                              \
    do {                                                                         \
        _Pragma("unroll")                                                        \
        for (int k = 0; k < 16; ++k) {                                           \
            const int   key = __builtin_amdgcn_readlane(mykey, (g) * 16 + k);    \
            const float wgt =                                                    \
                __int_as_float(__builtin_amdgcn_readlane(mywi, (g) * 16 + k));   \
            const int gcell = key >> 13;                                         \
            if (gcell != prev) {                      /* scalar branch */        \
                FLUSHP(prev);                                                    \
                acc = make_float2(0.0f, 0.0f);                                   \
                prev = gcell;                                                    \
            }                                                                    \
            acc.x = fmaf((float)V[k][0], wgt, acc.x);                            \
            acc.y = fmaf((float)V[k][1], wgt, acc.y);                            \
        }                                                                        \
    } while (0)

    half2v v0[16], v1[16], v2[16], v3[16];            // 64 rows in registers
    LOAD16(0, v0);                                    // issue ALL loads first
    LOAD16(1, v1);
    LOAD16(2, v2);
    LOAD16(3, v3);
    ACC16(0, v0);                                     // then accumulate in order
    ACC16(1, v1);
    ACC16(2, v2);
    ACC16(3, v3);
    FLUSHP(prev);

#undef LOAD16
#undef FLUSHP
#undef ACC16
}

// ---- K5: untranspose out_t[b][cell][c] -> out[b][c][cell] ----
__global__ __launch_bounds__(256) void k_untranspose(const float* __restrict__ out_t,
                                                     float* __restrict__ out) {
    __shared__ float tile[32][33];
    const int b = blockIdx.z;
    const int tx = threadIdx.x, ty = threadIdx.y;      // block (32, 8)
    const int cell0 = blockIdx.x * 32, c0 = blockIdx.y * 32;
    const float* src = out_t + (size_t)b * NCELL * C_DIM;
    #pragma unroll
    for (int j = 0; j < 32; j += 8)                    // read: c contiguous
        tile[ty + j][tx] = src[((size_t)(cell0 + ty + j)) * C_DIM + c0 + tx];
    __syncthreads();
    #pragma unroll
    for (int j = 0; j < 32; j += 8)                    // write: cell contiguous
        out[((size_t)(b * C_DIM + c0 + ty + j)) * NCELL + cell0 + tx] = tile[tx][ty + j];
}

extern "C" void kernel_launch(void* const* d_in, const int* in_sizes, int n_in,
                              void* d_out, int out_size, void* d_ws, size_t ws_size,
                              hipStream_t stream) {
    const float* img = (const float*)d_in[0];
    const float* dp  = (const float*)d_in[1];
    const float* dv  = (const float*)d_in[2];
    const float* K   = (const float*)d_in[3];
    const float* T   = (const float*)d_in[4];
    float* out = (float*)d_out;

    _Float16* img_t = (_Float16*)d_ws;                  // WS_IMG_T == 0
    int*   tot    = (int*)d_ws + WS_TOT;
    int*   hist2  = (int*)d_ws + WS_HIST2;
    float* out_t  = (float*)d_ws + WS_OUT_T;
    int*   offs   = (int*)d_ws + WS_OFFS;
    int*   ekey   = (int*)d_ws + WS_EKEY;
    unsigned short* ew16 = (unsigned short*)((int*)d_ws + WS_EW16);
    (void)ws_size;

    // zero tot + hist2 (contiguous, ~2.1 MB); out_t zeroed inside k_prep
    hipMemsetAsync(tot, 0, MEMSET_WORDS * sizeof(int), stream);

    k_prep<<<PREP_TOTAL, 256, 0, stream>>>(img, img_t, dv, K, T, hist2,
                                           (float4*)out_t);
    k_scan<<<SCAN_BLOCKS, 256, 0, stream>>>(hist2, offs, tot);
    k_fill<<<NPTS / 256, 256, 0, stream>>>(dp, dv, K, T, offs, hist2, ekey, ew16);
    constexpr int GATHER_BLOCKS = MAX_ENTRIES / (CHUNK * WAVES_PER_BLK);
    k_chunk_gather<<<GATHER_BLOCKS, 256, 0, stream>>>(img_t, offs, ekey, ew16, out_t);
    k_untranspose<<<dim3(NCELL / 32, C_DIM / 32, B_DIM), dim3(32, 8), 0, stream>>>(
        out_t, out);
}

// Round 13
// 141.490 us; speedup vs baseline: 1.0003x; 1.0003x over previous
//
#include <hip/hip_runtime.h>

// LSS view transform, chunked-gather formulation, sharded + wave-run binning.
// out[b,c,cell] = sum_{(pix,d)->cell} img[b,c,pix] * dp[b,d,pix]
// Round-21 (base = round-12, 141.5us). Gather diagnosis: 31 cyc/row-load =
// L2-miss serialization (img_t 7.86MB > 4MiB/XCD L2; scattered reads from all
// XCDs). Fix: XCD-batch affinity.
//  - blockIdx round-robins across XCDs (m09) -> parity (blockIdx&1) selects
//    disjoint XCD sets. Even-parity blocks process batch-0 chunks, odd ->
//    batch-1. Each XCD then reads only one 3.93MB img_t half < 4MiB L2 ->
//    L2-resident after warmup.
//  - out_t exclusive flushes + ekey/ew16 entry reads nontemporal (no L2
//    allocation -> img_t stays resident).
//  - batch boundary == cell boundary -> per-cell accumulation order unchanged.
//  - everything else byte-identical to round 12.
constexpr int IMG_H = 48, IMG_W = 160;
constexpr int HW    = IMG_H * IMG_W;          // 7680
constexpr int BEV_H = 128, BEV_W = 128;
constexpr int NCELL = BEV_H * BEV_W;          // 16384 per batch
constexpr int C_DIM = 128, D_DIM = 64, B_DIM = 2;
constexpr int NCELL_TOT = B_DIM * NCELL;      // 32768
constexpr int NPIX_TOT  = B_DIM * HW;         // 15360
constexpr int NPTS      = NPIX_TOT * D_DIM;   // 983040
constexpr int MAX_ENTRIES = NPTS;
constexpr int CHUNK = 64;
constexpr int WAVES_PER_BLK = 4;
constexpr int NSHARD = 16;
constexpr int CNT_BLOCKS = NPTS / 256;        // 3840
constexpr int TRN_BLOCKS = (HW / 32) * (C_DIM / 32) * B_DIM;  // 1920
constexpr int PREP_TOTAL = CNT_BLOCKS + TRN_BLOCKS;           // 5760
constexpr int SCAN_BLOCKS = NCELL_TOT / 256;  // 128
constexpr int GATHER_BLOCKS = MAX_ENTRIES / (CHUNK * WAVES_PER_BLK);  // 3840
constexpr float X_MIN = -51.2f, Y_MIN = -51.2f;
constexpr float RES_X = 102.4f / 128.0f;
constexpr float RES_Y = 102.4f / 128.0f;

typedef _Float16 half2v __attribute__((ext_vector_type(2)));

// ---- ws layout (4-byte words), ~28.8 MB total ----
constexpr size_t WS_IMG_T = 0;                                      // half[B*HW*C]
constexpr size_t WS_TOT   = WS_IMG_T + (size_t)B_DIM * HW * C_DIM / 2;  // int[4] [memset]
constexpr size_t WS_HIST2 = WS_TOT + 4;                             // int[16*32768] [memset, adjacent]
constexpr size_t WS_OUT_T = WS_HIST2 + (size_t)NSHARD * NCELL_TOT;  // float[32768*128] (zeroed by prep)
constexpr size_t WS_OFFS  = WS_OUT_T + (size_t)NCELL_TOT * C_DIM;   // int[32769]+pad
constexpr size_t WS_EKEY  = WS_OFFS + NCELL_TOT + 4;                // int[NPTS]
constexpr size_t WS_EW16  = WS_EKEY + MAX_ENTRIES;                  // ushort[NPTS]
constexpr size_t MEMSET_WORDS = 4 + (size_t)NSHARD * NCELL_TOT;     // ~2.1 MB
constexpr int OUT_T_F4 = NCELL_TOT * C_DIM / 4;                     // 1048576 float4s

__device__ inline int point_shard(int tid) {
    return ((tid >> 2) + (tid >> 8)) & (NSHARD - 1);   // deterministic in tid
}

__device__ inline void make_ray(const float* __restrict__ K, int b, float gx, float gy,
                                float& rx, float& ry, float& rz) {
    const float* Kb = K + b * 9;
    const float a00 = Kb[0], a01 = Kb[1], a02 = Kb[2];
    const float a10 = Kb[3], a11 = Kb[4], a12 = Kb[5];
    const float a20 = Kb[6], a21 = Kb[7], a22 = Kb[8];
    const float det = a00 * (a11 * a22 - a12 * a21)
                    - a01 * (a10 * a22 - a12 * a20)
                    + a02 * (a10 * a21 - a11 * a20);
    const float inv = 1.0f / det;
    const float i00 =  (a11 * a22 - a12 * a21) * inv;
    const float i01 = -(a01 * a22 - a02 * a21) * inv;
    const float i02 =  (a01 * a12 - a02 * a11) * inv;
    const float i10 = -(a10 * a22 - a12 * a20) * inv;
    const float i11 =  (a00 * a22 - a02 * a20) * inv;
    const float i12 = -(a00 * a12 - a02 * a10) * inv;
    const float i20 =  (a10 * a21 - a11 * a20) * inv;
    const float i21 = -(a00 * a21 - a01 * a20) * inv;
    const float i22 =  (a00 * a11 - a01 * a10) * inv;
    rx = i00 * gx + i01 * gy + i02;
    ry = i10 * gx + i11 * gy + i12;
    rz = i20 * gx + i21 * gy + i22;
}

// Returns global cell id (b*NCELL + cell) or -1. tid = ((b*D + d)*HW + pix).
__device__ inline int point_gcell(int tid, const float* __restrict__ dv,
                                  const float* __restrict__ K,
                                  const float* __restrict__ T) {
    const int pix = tid % HW;
    const int bd  = tid / HW;
    const int d   = bd % D_DIM;
    const int b   = bd / D_DIM;
    const int h = pix / IMG_W, w = pix % IMG_W;
    float rx, ry, rz;
    make_ray(K, b, (float)w, (float)h, rx, ry, rz);
    const float* Tb = T + b * 16;
    const float dep = dv[d];                       // wave-uniform
    const float px = dep * rx, py = dep * ry, pz = dep * rz;
    const float x = Tb[0] * px + Tb[1] * py + Tb[2]  * pz + Tb[3];
    const float y = Tb[4] * px + Tb[5] * py + Tb[6]  * pz + Tb[7];
    const float z = Tb[8] * px + Tb[9] * py + Tb[10] * pz + Tb[11];
    const int bx = (int)((x - X_MIN) / RES_X);     // truncate-toward-zero == astype(int32)
    const int by = (int)((y - Y_MIN) / RES_Y);
    const bool valid = (bx >= 0) && (bx < BEV_W) && (by >= 0) && (by < BEV_H) && (z > 0.0f);
    return valid ? (b * NCELL + by * BEV_W + bx) : -1;
}

// Wave-run helpers: lanes are consecutive pixels -> equal-cell runs.
__device__ inline bool wave_runs(int gcell, int lane, int& run_len, int& leader_idx) {
    const int left = __shfl_up(gcell, 1);          // width 64
    const bool is_leader = (lane == 0) || (left != gcell);
    const unsigned long long lmask = __ballot(is_leader);
    const unsigned long long rest = (lane == 63) ? 0ULL : (lmask >> (lane + 1));
    const int f = __ffsll((unsigned long long)rest);   // 1+idx or 0
    run_len = f ? f : (64 - lane);
    const unsigned long long below =
        lmask & ((lane == 63) ? ~0ULL : ((1ULL << (lane + 1)) - 1ULL));
    leader_idx = 63 - __clzll((long long)below);
    return is_leader;
}

// ---- K1: fused {sharded count | transpose/fp16 | out_t zero} ----
__global__ __launch_bounds__(256) void k_prep(const float* __restrict__ img,
                                              _Float16* __restrict__ img_t,
                                              const float* __restrict__ dv,
                                              const float* __restrict__ K,
                                              const float* __restrict__ T,
                                              int* __restrict__ hist2,
                                              float4* __restrict__ out_t4) {
    __shared__ float tile[32][33];
    const int t = threadIdx.x;

    // zero out_t stripe (grid covers all of it; <=1 float4 per thread)
    {
        const int i = blockIdx.x * 256 + t;
        if (i < OUT_T_F4) out_t4[i] = make_float4(0.f, 0.f, 0.f, 0.f);
    }

    if (blockIdx.x < CNT_BLOCKS) {
        const int tid = blockIdx.x * 256 + t;             // < NPTS (exact)
        const int gcell = point_gcell(tid, dv, K, T);
        const int lane = t & 63;
        int run_len, leader_idx;
        const bool lead = wave_runs(gcell, lane, run_len, leader_idx);
        if (lead && gcell >= 0)
            atomicAdd(&hist2[(size_t)point_shard(tid) * NCELL_TOT + gcell], run_len);
    } else {
        const int bi = blockIdx.x - CNT_BLOCKS;
        const int px_t = bi % (HW / 32);
        const int c_t  = (bi / (HW / 32)) % (C_DIM / 32);
        const int b    = bi / ((HW / 32) * (C_DIM / 32));
        const int tx = t & 31, ty = t >> 5;               // (32,8)
        const int pix0 = px_t * 32, c0 = c_t * 32;
        #pragma unroll
        for (int j = 0; j < 32; j += 8)
            tile[ty + j][tx] = img[((size_t)(b * C_DIM + c0 + ty + j)) * HW + pix0 + tx];
        __syncthreads();
        #pragma unroll
        for (int j = 0; j < 32; j += 8)
            img_t[((size_t)(b * HW + pix0 + ty + j)) * C_DIM + c0 + tx] =
                (_Float16)tile[tx][ty + j];
    }
}

// ---- K2: fence-free scan. Shard-reduce + in-place local prefix; block scan;
// base claimed in ARRIVAL order via relaxed atomicAdd (entry ranges need
// disjointness, not cell order). 128th arriver publishes offs[NCELL_TOT].
// NOTE: blocks 0..63 (batch 0 cells) and 64..127 (batch 1) claim bases in
// arrival order; entries of the two batches may interleave in ekey, but
// offs[] is still a correct disjoint partition. Batch membership of an entry
// is carried by its key, and gather partitions chunks by offs[NCELL]... so
// batch-0 bases MUST precede batch-1 bases. Enforce: blocks 0..63 add to
// tot[0] as before; blocks 64..127 add to tot[2] (second counter), and the
// final offsets for batch-1 are biased by the FULL batch-0 total, known only
// after all 64 batch-0 blocks arrive -> instead, simpler: claim bases within
// batch region: batch-0 blocks use tot[0] (region starts at 0), batch-1
// blocks use tot[2] with region start = exact batch-0 total. To know it
// without ordering, batch-1 cells' entries are placed from the TOP of the
// array downward: batch-1 block base = NPTS - tot[2] - S, descending. Then
// offs[NCELL] = batch-0 total is NOT the batch-1 start; gather's split uses
// offs[NCELL_TOT+1]... — complexity not worth it. Instead batch-1 entries
// start at fixed midpoint NPTS/2 (each batch has exactly NPTS/2 points, so
// batch totals <= NPTS/2 always fit).
__global__ __launch_bounds__(256) void k_scan(int* __restrict__ hist2,
                                              int* __restrict__ offs,
                                              int* __restrict__ tot) {
    __shared__ int lds[256];
    __shared__ int s_base;
    const int b = blockIdx.x;                      // 128 blocks
    const int t = threadIdx.x;                     // 256 threads
    const int cell = b * 256 + t;
    const int batch = b >> 6;                      // 0: cells<16384, 1: rest
    // shard reduce + in-place local exclusive prefix (coalesced sweeps)
    int run = 0;
    #pragma unroll
    for (int sh = 0; sh < NSHARD; ++sh) {
        const size_t idx = (size_t)sh * NCELL_TOT + cell;
        const int c = hist2[idx];
        hist2[idx] = run;          // local exclusive prefix (cursor base for fill)
        run += c;
    }
    const int h = run;                             // cell total
    // inclusive block scan
    lds[t] = h;
    __syncthreads();
    #pragma unroll
    for (int off = 1; off < 256; off <<= 1) {
        const int v = (t >= off) ? lds[t - off] : 0;
        __syncthreads();
        lds[t] += v;
        __syncthreads();
    }
    const int incl = lds[t];
    const int S = lds[255];                        // block aggregate
    if (t == 0) {
        // per-batch region: batch 0 entries in [0, n0), batch 1 in
        // [NPTS/2, NPTS/2 + n1). Arrival-order base claim within region.
        s_base = (batch ? NPTS / 2 : 0) + atomicAdd(&tot[batch * 2], S);
        const int arr = atomicAdd(&tot[1], 1);
        if (arr == SCAN_BLOCKS - 1) {              // last arrival: all adds landed
            offs[NCELL_TOT] = atomicAdd(&tot[0], 0);       // batch-0 count n0
            offs[NCELL_TOT + 1] = atomicAdd(&tot[2], 0);   // batch-1 count n1
        }
    }
    __syncthreads();
    offs[cell] = s_base + incl - h;                // global exclusive prefix
}

// ---- K3: fill entries; leader reserves span via offs + local shard cursor ----
__global__ __launch_bounds__(256) void k_fill(const float* __restrict__ dp,
                                              const float* __restrict__ dv,
                                              const float* __restrict__ K,
                                              const float* __restrict__ T,
                                              const int* __restrict__ offs,
                                              int* __restrict__ cursor2,   // = hist2 (local prefix)
                                              int* __restrict__ ekey,
                                              unsigned short* __restrict__ ew16) {
    const int tid = blockIdx.x * 256 + threadIdx.x;   // < NPTS (exact grid)
    const int gcell = point_gcell(tid, dv, K, T);
    const int lane = threadIdx.x & 63;
    int run_len, leader_idx;
    const bool lead = wave_runs(gcell, lane, run_len, leader_idx);
    int base = 0;
    if (lead && gcell >= 0)
        base = offs[gcell]
             + atomicAdd(&cursor2[(size_t)point_shard(tid) * NCELL_TOT + gcell], run_len);
    base = __shfl(base, leader_idx);                  // broadcast my run's base
    if (gcell < 0) return;
    const int slot = base + (lane - leader_idx);      // contiguous, coalesced writes
    const float p = dp[tid];                          // tid == ((b*D+d)*HW+pix): coalesced
    ekey[slot] = (gcell << 13) | (tid % HW);
    ew16[slot] = (unsigned short)__float2uint_rn(p * 65535.0f);
}

// ---- K4: chunked segmented reduction with XCD-batch affinity.
// Even-parity blocks (XCDs 0,2,4,6 under round-robin blockIdx->XCD) process
// batch-0 chunks [0, n0); odd-parity blocks process batch-1 chunks
// [NPTS/2, NPTS/2 + n1). Each XCD reads only one 3.93MB img_t half -> fits
// 4MiB L2. Entry reads + exclusive flushes nontemporal (no L2 pollution).
// All 64 row loads issued before accumulation (R12 max-MLP body).
__global__ __launch_bounds__(256) void k_chunk_gather(
    const _Float16* __restrict__ img_t,
    const int* __restrict__ offs,
    const int* __restrict__ ekey,
    const unsigned short* __restrict__ ew16,
    float* __restrict__ out_t)
{
    const int n0 = offs[NCELL_TOT];
    const int n1 = offs[NCELL_TOT + 1];
    const int wave  = threadIdx.x >> 6;
    const int lane  = threadIdx.x & 63;
    const int p     = blockIdx.x & 1;              // XCD parity
    const int j     = blockIdx.x >> 1;
    const int start = p ? (NPTS / 2) : 0;
    const int limit = start + (p ? n1 : n0);
    const int nch   = ((p ? n1 : n0) + CHUNK - 1) >> 6;
    const int c2 = lane * 2;                       // channels c2, c2+1

    for (int c = (j << 2) + wave; c < nch; c += (GATHER_BLOCKS >> 1) << 2) {
        const int base = start + c * CHUNK;
        // per-lane entry fetch (coalesced, nontemporal); pad = dup last, w 0
        const int eidx = min(base + lane, limit - 1);
        const int   mykey = __builtin_nontemporal_load(&ekey[eidx]);
        const float myw   = (base + lane < limit)
            ? (float)__builtin_nontemporal_load(&ew16[base + lane]) * (1.0f / 65535.0f)
            : 0.0f;
        const int mywi = __float_as_int(myw);

        const int fc    = __builtin_amdgcn_readlane(mykey, 0) >> 13;   // first cell
        const int lcell = __builtin_amdgcn_readlane(mykey, 63) >> 13;  // last cell
        const bool shared_first = (base > start) && ((ekey[base - 1] >> 13) == fc);
        const bool shared_last  = (base + CHUNK < limit) &&
                                  ((ekey[base + CHUNK] >> 13) == lcell);

        int prev = fc;
        float2 acc = make_float2(0.0f, 0.0f);

#define LOAD16(g, V)                                                             \
    do {                                                                         \
        _Pragma("unroll")                                                        \
        for (int k = 0; k < 16; ++k) {                                           \
            const int key = __builtin_amdgcn_readlane(mykey, (g) * 16 + k);      \
            const int pix = key & 8191;                                          \
            const int bb  = key >> 27;                                           \
            V[k] = *reinterpret_cast<const half2v*>(                             \
                &img_t[((size_t)(bb * HW + pix)) * C_DIM + c2]);                 \
        }                                                                        \
    } while (0)

#define FLUSHP(cell)                                                             \
    do {                                                                         \
        float* o = &out_t[(size_t)(cell) * C_DIM + c2];                          \
        const bool shared_ = ((cell) == fc && shared_first) ||                   \
                             ((cell) == lcell && shared_last);                   \
        if (shared_) {                                                           \
            atomicAdd(o, acc.x);                                                 \
            atomicAdd(o + 1, acc.y);                                             \
        } else {                                                                 \
            __builtin_nontemporal_store(*reinterpret_cast<double*>(&acc),        \
                                        reinterpret_cast<double*>(o));           \
        }                                                                        \
    } while (0)

#define ACC16(g, V)                                                              \
    do {                                                                         \
        _Pragma("unroll")                                                        \
        for (int k = 0; k < 16; ++k) {                                           \
            const int   key = __builtin_amdgcn_readlane(mykey, (g) * 16 + k);    \
            const float wgt =                                                    \
                __int_as_float(__builtin_amdgcn_readlane(mywi, (g) * 16 + k));   \
            const int gcell = key >> 13;                                         \
            if (gcell != prev) {                      /* scalar branch */        \
                FLUSHP(prev);                                                    \
                acc = make_float2(0.0f, 0.0f);                                   \
                prev = gcell;                                                    \
            }                                                                    \
            acc.x = fmaf((float)V[k][0], wgt, acc.x);                            \
            acc.y = fmaf((float)V[k][1], wgt, acc.y);                            \
        }                                                                        \
    } while (0)

        half2v v0[16], v1[16], v2[16], v3[16];        // 64 rows in registers
        LOAD16(0, v0);                                // issue ALL loads first
        LOAD16(1, v1);
        LOAD16(2, v2);
        LOAD16(3, v3);
        ACC16(0, v0);                                 // then accumulate in order
        ACC16(1, v1);
        ACC16(2, v2);
        ACC16(3, v3);
        FLUSHP(prev);

#undef LOAD16
#undef FLUSHP
#undef ACC16
    }
}

// ---- K5: untranspose out_t[b][cell][c] -> out[b][c][cell] ----
__global__ __launch_bounds__(256) void k_untranspose(const float* __restrict__ out_t,
                                                     float* __restrict__ out) {
    __shared__ float tile[32][33];
    const int b = blockIdx.z;
    const int tx = threadIdx.x, ty = threadIdx.y;      // block (32, 8)
    const int cell0 = blockIdx.x * 32, c0 = blockIdx.y * 32;
    const float* src = out_t + (size_t)b * NCELL * C_DIM;
    #pragma unroll
    for (int j = 0; j < 32; j += 8)                    // read: c contiguous
        tile[ty + j][tx] = src[((size_t)(cell0 + ty + j)) * C_DIM + c0 + tx];
    __syncthreads();
    #pragma unroll
    for (int j = 0; j < 32; j += 8)                    // write: cell contiguous
        out[((size_t)(b * C_DIM + c0 + ty + j)) * NCELL + cell0 + tx] = tile[tx][ty + j];
}

extern "C" void kernel_launch(void* const* d_in, const int* in_sizes, int n_in,
                              void* d_out, int out_size, void* d_ws, size_t ws_size,
                              hipStream_t stream) {
    const float* img = (const float*)d_in[0];
    const float* dp  = (const float*)d_in[1];
    const float* dv  = (const float*)d_in[2];
    const float* K   = (const float*)d_in[3];
    const float* T   = (const float*)d_in[4];
    float* out = (float*)d_out;

    _Float16* img_t = (_Float16*)d_ws;                  // WS_IMG_T == 0
    int*   tot    = (int*)d_ws + WS_TOT;
    int*   hist2  = (int*)d_ws + WS_HIST2;
    float* out_t  = (float*)d_ws + WS_OUT_T;
    int*   offs   = (int*)d_ws + WS_OFFS;
    int*   ekey   = (int*)d_ws + WS_EKEY;
    unsigned short* ew16 = (unsigned short*)((int*)d_ws + WS_EW16);
    (void)ws_size;

    // zero tot + hist2 (contiguous, ~2.1 MB); out_t zeroed inside k_prep
    hipMemsetAsync(tot, 0, MEMSET_WORDS * sizeof(int), stream);

    k_prep<<<PREP_TOTAL, 256, 0, stream>>>(img, img_t, dv, K, T, hist2,
                                           (float4*)out_t);
    k_scan<<<SCAN_BLOCKS, 256, 0, stream>>>(hist2, offs, tot);
    k_fill<<<NPTS / 256, 256, 0, stream>>>(dp, dv, K, T, offs, hist2, ekey, ew16);
    k_chunk_gather<<<GATHER_BLOCKS, 256, 0, stream>>>(img_t, offs, ekey, ew16, out_t);
    k_untranspose<<<dim3(NCELL / 32, C_DIM / 32, B_DIM), dim3(32, 8), 0, stream>>>(
        out_t, out);
}

// Round 14
// 134.248 us; speedup vs baseline: 1.0543x; 1.0539x over previous
//
#include <hip/hip_runtime.h>

// LSS view transform, chunked-gather formulation, sharded + wave-run binning.
// out[b,c,cell] = sum_{(pix,d)->cell} img[b,c,pix] * dp[b,d,pix]
// Round-22 (base = round-11/12, 141.0us). Elimination so far: gather is not
// VALU/HBM/L2-capacity/MLP-bound (R11-R13). Remaining pool: ~4M per-dword
// L2 RMW flush atomics (95% of flushes are chunk-boundary at CHUNK=64 with
// ~30 entries/cell). Lever: CHUNK 64 -> 256 per wave (boundary flushes are
// 2/chunk regardless of length -> atomic dwords ~/4; interior cells become
// plain contiguous 512B stores). Accumulation order over entries unchanged.
// Also reverted R13's null complexity (two-region scan, nontemporal).
constexpr int IMG_H = 48, IMG_W = 160;
constexpr int HW    = IMG_H * IMG_W;          // 7680
constexpr int BEV_H = 128, BEV_W = 128;
constexpr int NCELL = BEV_H * BEV_W;          // 16384 per batch
constexpr int C_DIM = 128, D_DIM = 64, B_DIM = 2;
constexpr int NCELL_TOT = B_DIM * NCELL;      // 32768
constexpr int NPIX_TOT  = B_DIM * HW;         // 15360
constexpr int NPTS      = NPIX_TOT * D_DIM;   // 983040
constexpr int MAX_ENTRIES = NPTS;
constexpr int BIGCHUNK = 256;                 // entries per wave
constexpr int WAVES_PER_BLK = 4;
constexpr int NSHARD = 16;
constexpr int CNT_BLOCKS = NPTS / 256;        // 3840
constexpr int TRN_BLOCKS = (HW / 32) * (C_DIM / 32) * B_DIM;  // 1920
constexpr int PREP_TOTAL = CNT_BLOCKS + TRN_BLOCKS;           // 5760
constexpr int SCAN_BLOCKS = NCELL_TOT / 256;  // 128
constexpr int GATHER_BLOCKS = NPTS / (BIGCHUNK * WAVES_PER_BLK);  // 960
constexpr float X_MIN = -51.2f, Y_MIN = -51.2f;
constexpr float RES_X = 102.4f / 128.0f;
constexpr float RES_Y = 102.4f / 128.0f;

typedef _Float16 half2v __attribute__((ext_vector_type(2)));

// ---- ws layout (4-byte words), ~28.8 MB total ----
constexpr size_t WS_IMG_T = 0;                                      // half[B*HW*C]
constexpr size_t WS_TOT   = WS_IMG_T + (size_t)B_DIM * HW * C_DIM / 2;  // int[4] [memset]
constexpr size_t WS_HIST2 = WS_TOT + 4;                             // int[16*32768] [memset, adjacent]
constexpr size_t WS_OUT_T = WS_HIST2 + (size_t)NSHARD * NCELL_TOT;  // float[32768*128] (zeroed by prep)
constexpr size_t WS_OFFS  = WS_OUT_T + (size_t)NCELL_TOT * C_DIM;   // int[32769]+pad
constexpr size_t WS_EKEY  = WS_OFFS + NCELL_TOT + 4;                // int[NPTS]
constexpr size_t WS_EW16  = WS_EKEY + MAX_ENTRIES;                  // ushort[NPTS]
constexpr size_t MEMSET_WORDS = 4 + (size_t)NSHARD * NCELL_TOT;     // ~2.1 MB
constexpr int OUT_T_F4 = NCELL_TOT * C_DIM / 4;                     // 1048576 float4s

__device__ inline int point_shard(int tid) {
    return ((tid >> 2) + (tid >> 8)) & (NSHARD - 1);   // deterministic in tid
}

__device__ inline void make_ray(const float* __restrict__ K, int b, float gx, float gy,
                                float& rx, float& ry, float& rz) {
    const float* Kb = K + b * 9;
    const float a00 = Kb[0], a01 = Kb[1], a02 = Kb[2];
    const float a10 = Kb[3], a11 = Kb[4], a12 = Kb[5];
    const float a20 = Kb[6], a21 = Kb[7], a22 = Kb[8];
    const float det = a00 * (a11 * a22 - a12 * a21)
                    - a01 * (a10 * a22 - a12 * a20)
                    + a02 * (a10 * a21 - a11 * a20);
    const float inv = 1.0f / det;
    const float i00 =  (a11 * a22 - a12 * a21) * inv;
    const float i01 = -(a01 * a22 - a02 * a21) * inv;
    const float i02 =  (a01 * a12 - a02 * a11) * inv;
    const float i10 = -(a10 * a22 - a12 * a20) * inv;
    const float i11 =  (a00 * a22 - a02 * a20) * inv;
    const float i12 = -(a00 * a12 - a02 * a10) * inv;
    const float i20 =  (a10 * a21 - a11 * a20) * inv;
    const float i21 = -(a00 * a21 - a01 * a20) * inv;
    const float i22 =  (a00 * a11 - a01 * a10) * inv;
    rx = i00 * gx + i01 * gy + i02;
    ry = i10 * gx + i11 * gy + i12;
    rz = i20 * gx + i21 * gy + i22;
}

// Returns global cell id (b*NCELL + cell) or -1. tid = ((b*D + d)*HW + pix).
__device__ inline int point_gcell(int tid, const float* __restrict__ dv,
                                  const float* __restrict__ K,
                                  const float* __restrict__ T) {
    const int pix = tid % HW;
    const int bd  = tid / HW;
    const int d   = bd % D_DIM;
    const int b   = bd / D_DIM;
    const int h = pix / IMG_W, w = pix % IMG_W;
    float rx, ry, rz;
    make_ray(K, b, (float)w, (float)h, rx, ry, rz);
    const float* Tb = T + b * 16;
    const float dep = dv[d];                       // wave-uniform
    const float px = dep * rx, py = dep * ry, pz = dep * rz;
    const float x = Tb[0] * px + Tb[1] * py + Tb[2]  * pz + Tb[3];
    const float y = Tb[4] * px + Tb[5] * py + Tb[6]  * pz + Tb[7];
    const float z = Tb[8] * px + Tb[9] * py + Tb[10] * pz + Tb[11];
    const int bx = (int)((x - X_MIN) / RES_X);     // truncate-toward-zero == astype(int32)
    const int by = (int)((y - Y_MIN) / RES_Y);
    const bool valid = (bx >= 0) && (bx < BEV_W) && (by >= 0) && (by < BEV_H) && (z > 0.0f);
    return valid ? (b * NCELL + by * BEV_W + bx) : -1;
}

// Wave-run helpers: lanes are consecutive pixels -> equal-cell runs.
__device__ inline bool wave_runs(int gcell, int lane, int& run_len, int& leader_idx) {
    const int left = __shfl_up(gcell, 1);          // width 64
    const bool is_leader = (lane == 0) || (left != gcell);
    const unsigned long long lmask = __ballot(is_leader);
    const unsigned long long rest = (lane == 63) ? 0ULL : (lmask >> (lane + 1));
    const int f = __ffsll((unsigned long long)rest);   // 1+idx or 0
    run_len = f ? f : (64 - lane);
    const unsigned long long below =
        lmask & ((lane == 63) ? ~0ULL : ((1ULL << (lane + 1)) - 1ULL));
    leader_idx = 63 - __clzll((long long)below);
    return is_leader;
}

// ---- K1: fused {sharded count | transpose/fp16 | out_t zero} ----
__global__ __launch_bounds__(256) void k_prep(const float* __restrict__ img,
                                              _Float16* __restrict__ img_t,
                                              const float* __restrict__ dv,
                                              const float* __restrict__ K,
                                              const float* __restrict__ T,
                                              int* __restrict__ hist2,
                                              float4* __restrict__ out_t4) {
    __shared__ float tile[32][33];
    const int t = threadIdx.x;

    // zero out_t stripe (grid covers all of it; <=1 float4 per thread)
    {
        const int i = blockIdx.x * 256 + t;
        if (i < OUT_T_F4) out_t4[i] = make_float4(0.f, 0.f, 0.f, 0.f);
    }

    if (blockIdx.x < CNT_BLOCKS) {
        const int tid = blockIdx.x * 256 + t;             // < NPTS (exact)
        const int gcell = point_gcell(tid, dv, K, T);
        const int lane = t & 63;
        int run_len, leader_idx;
        const bool lead = wave_runs(gcell, lane, run_len, leader_idx);
        if (lead && gcell >= 0)
            atomicAdd(&hist2[(size_t)point_shard(tid) * NCELL_TOT + gcell], run_len);
    } else {
        const int bi = blockIdx.x - CNT_BLOCKS;
        const int px_t = bi % (HW / 32);
        const int c_t  = (bi / (HW / 32)) % (C_DIM / 32);
        const int b    = bi / ((HW / 32) * (C_DIM / 32));
        const int tx = t & 31, ty = t >> 5;               // (32,8)
        const int pix0 = px_t * 32, c0 = c_t * 32;
        #pragma unroll
        for (int j = 0; j < 32; j += 8)
            tile[ty + j][tx] = img[((size_t)(b * C_DIM + c0 + ty + j)) * HW + pix0 + tx];
        __syncthreads();
        #pragma unroll
        for (int j = 0; j < 32; j += 8)
            img_t[((size_t)(b * HW + pix0 + ty + j)) * C_DIM + c0 + tx] =
                (_Float16)tile[tx][ty + j];
    }
}

// ---- K2: fence-free scan. Shard-reduce + in-place local prefix; block scan;
// base claimed in ARRIVAL order via relaxed atomicAdd (entry ranges need
// disjointness, not cell order). 128th arriver publishes offs[NCELL_TOT].
__global__ __launch_bounds__(256) void k_scan(int* __restrict__ hist2,
                                              int* __restrict__ offs,
                                              int* __restrict__ tot) {
    __shared__ int lds[256];
    __shared__ int s_base;
    const int b = blockIdx.x;                      // 128 blocks
    const int t = threadIdx.x;                     // 256 threads
    const int cell = b * 256 + t;
    // shard reduce + in-place local exclusive prefix (coalesced sweeps)
    int run = 0;
    #pragma unroll
    for (int sh = 0; sh < NSHARD; ++sh) {
        const size_t idx = (size_t)sh * NCELL_TOT + cell;
        const int c = hist2[idx];
        hist2[idx] = run;          // local exclusive prefix (cursor base for fill)
        run += c;
    }
    const int h = run;                             // cell total
    // inclusive block scan
    lds[t] = h;
    __syncthreads();
    #pragma unroll
    for (int off = 1; off < 256; off <<= 1) {
        const int v = (t >= off) ? lds[t - off] : 0;
        __syncthreads();
        lds[t] += v;
        __syncthreads();
    }
    const int incl = lds[t];
    const int S = lds[255];                        // block aggregate
    if (t == 0) {
        s_base = atomicAdd(&tot[0], S);            // relaxed, arrival order
        const int arr = atomicAdd(&tot[1], 1);
        if (arr == SCAN_BLOCKS - 1)                // last arrival: all adds landed
            offs[NCELL_TOT] = atomicAdd(&tot[0], 0);   // read final total
    }
    __syncthreads();
    offs[cell] = s_base + incl - h;                // global exclusive prefix
}

// ---- K3: fill entries; leader reserves span via offs + local shard cursor ----
__global__ __launch_bounds__(256) void k_fill(const float* __restrict__ dp,
                                              const float* __restrict__ dv,
                                              const float* __restrict__ K,
                                              const float* __restrict__ T,
                                              const int* __restrict__ offs,
                                              int* __restrict__ cursor2,   // = hist2 (local prefix)
                                              int* __restrict__ ekey,
                                              unsigned short* __restrict__ ew16) {
    const int tid = blockIdx.x * 256 + threadIdx.x;   // < NPTS (exact grid)
    const int gcell = point_gcell(tid, dv, K, T);
    const int lane = threadIdx.x & 63;
    int run_len, leader_idx;
    const bool lead = wave_runs(gcell, lane, run_len, leader_idx);
    int base = 0;
    if (lead && gcell >= 0)
        base = offs[gcell]
             + atomicAdd(&cursor2[(size_t)point_shard(tid) * NCELL_TOT + gcell], run_len);
    base = __shfl(base, leader_idx);                  // broadcast my run's base
    if (gcell < 0) return;
    const int slot = base + (lane - leader_idx);      // contiguous, coalesced writes
    const float p = dp[tid];                          // tid == ((b*D+d)*HW+pix): coalesced
    ekey[slot] = (gcell << 13) | (tid % HW);
    ew16[slot] = (unsigned short)__float2uint_rn(p * 65535.0f);
}

// ---- K4: chunked segmented reduction, BIGCHUNK=256 entries per wave
// (4 sub-chunks of 64; acc/prev carried across sub-chunks -> accumulation
// order over entries identical to CHUNK=64). Boundary (atomic) flushes are
// 2 per 256-entry chunk instead of 2 per 64 -> atomic dwords ~/4. Interior
// cells flush with plain contiguous 512B stores (cell-major out_t).
__global__ __launch_bounds__(256) void k_chunk_gather(
    const _Float16* __restrict__ img_t,
    const int* __restrict__ offs,     // offs[NCELL_TOT] = total entry count
    const int* __restrict__ ekey,
    const unsigned short* __restrict__ ew16,
    float* __restrict__ out_t)
{
    const int total = offs[NCELL_TOT];
    const int wave  = threadIdx.x >> 6;
    const int lane  = threadIdx.x & 63;
    const int ci    = blockIdx.x * WAVES_PER_BLK + wave;
    const int nch   = (total + BIGCHUNK - 1) / BIGCHUNK;
    if (ci >= nch) return;
    const int base  = ci * BIGCHUNK;
    const int c2    = lane * 2;                       // channels c2, c2+1

    // per-lane entry fetch for 4 sub-chunks (coalesced); pad: dup last, w 0
    int mykey0, mykey1, mykey2, mykey3;
    int mywi0, mywi1, mywi2, mywi3;
#define LOADKEYS(S, KV, WV)                                                      \
    do {                                                                         \
        const int idx = base + (S) * 64 + lane;                                  \
        const int eidx = min(idx, total - 1);                                    \
        KV = ekey[eidx];                                                         \
        const float w = (idx < total) ? (float)ew16[eidx] * (1.0f / 65535.0f)    \
                                      : 0.0f;                                    \
        WV = __float_as_int(w);                                                  \
    } while (0)
    LOADKEYS(0, mykey0, mywi0);
    LOADKEYS(1, mykey1, mywi1);
    LOADKEYS(2, mykey2, mywi2);
    LOADKEYS(3, mykey3, mywi3);
#undef LOADKEYS

    const int fc    = __builtin_amdgcn_readlane(mykey0, 0) >> 13;   // first cell
    const int lcell = __builtin_amdgcn_readlane(mykey3, 63) >> 13;  // last cell
    // boundary-continuation flags (uniform scalar loads, broadcast by cache)
    const bool shared_first = (base > 0) && ((ekey[base - 1] >> 13) == fc);
    const bool shared_last  = (base + BIGCHUNK < total) &&
                              ((ekey[base + BIGCHUNK] >> 13) == lcell);

    int prev = fc;
    float2 acc = make_float2(0.0f, 0.0f);

#define LOAD16(KV, g, V)                                                         \
    do {                                                                         \
        _Pragma("unroll")                                                        \
        for (int k = 0; k < 16; ++k) {                                           \
            const int key = __builtin_amdgcn_readlane(KV, (g) * 16 + k);         \
            const int pix = key & 8191;                                          \
            const int bb  = key >> 27;                                           \
            V[k] = *reinterpret_cast<const half2v*>(                             \
                &img_t[((size_t)(bb * HW + pix)) * C_DIM + c2]);                 \
        }                                                                        \
    } while (0)

#define FLUSHP(cell)                                                             \
    do {                                                                         \
        float* o = &out_t[(size_t)(cell) * C_DIM + c2];                          \
        const bool shared_ = ((cell) == fc && shared_first) ||                   \
                             ((cell) == lcell && shared_last);                   \
        if (shared_) {                                                           \
            atomicAdd(o, acc.x);                                                 \
            atomicAdd(o + 1, acc.y);                                             \
        } else {                                                                 \
            *reinterpret_cast<float2*>(o) = acc;  /* exclusive owner */          \
        }                                                                        \
    } while (0)

#define ACC16(KV, WV, g, V)                                                      \
    do {                                                                         \
        _Pragma("unroll")                                                        \
        for (int k = 0; k < 16; ++k) {                                           \
            const int   key = __builtin_amdgcn_readlane(KV, (g) * 16 + k);       \
            const float wgt =                                                    \
                __int_as_float(__builtin_amdgcn_readlane(WV, (g) * 16 + k));     \
            const int gcell = key >> 13;                                         \
            if (gcell != prev) {                      /* scalar branch */        \
                FLUSHP(prev);                                                    \
                acc = make_float2(0.0f, 0.0f);                                   \
                prev = gcell;                                                    \
            }                                                                    \
            acc.x = fmaf((float)V[k][0], wgt, acc.x);                            \
            acc.y = fmaf((float)V[k][1], wgt, acc.y);                            \
        }                                                                        \
    } while (0)

#define SUB64(KV, WV)                                                            \
    do {                                                                         \
        half2v v0[16], v1[16], v2[16], v3[16];                                   \
        LOAD16(KV, 0, v0);                                                       \
        LOAD16(KV, 1, v1);                                                       \
        LOAD16(KV, 2, v2);                                                       \
        LOAD16(KV, 3, v3);                                                       \
        ACC16(KV, WV, 0, v0);                                                    \
        ACC16(KV, WV, 1, v1);                                                    \
        ACC16(KV, WV, 2, v2);                                                    \
        ACC16(KV, WV, 3, v3);                                                    \
    } while (0)

    SUB64(mykey0, mywi0);
    SUB64(mykey1, mywi1);
    SUB64(mykey2, mywi2);
    SUB64(mykey3, mywi3);
    FLUSHP(prev);

#undef LOAD16
#undef FLUSHP
#undef ACC16
#undef SUB64
}

// ---- K5: untranspose out_t[b][cell][c] -> out[b][c][cell] ----
__global__ __launch_bounds__(256) void k_untranspose(const float* __restrict__ out_t,
                                                     float* __restrict__ out) {
    __shared__ float tile[32][33];
    const int b = blockIdx.z;
    const int tx = threadIdx.x, ty = threadIdx.y;      // block (32, 8)
    const int cell0 = blockIdx.x * 32, c0 = blockIdx.y * 32;
    const float* src = out_t + (size_t)b * NCELL * C_DIM;
    #pragma unroll
    for (int j = 0; j < 32; j += 8)                    // read: c contiguous
        tile[ty + j][tx] = src[((size_t)(cell0 + ty + j)) * C_DIM + c0 + tx];
    __syncthreads();
    #pragma unroll
    for (int j = 0; j < 32; j += 8)                    // write: cell contiguous
        out[((size_t)(b * C_DIM + c0 + ty + j)) * NCELL + cell0 + tx] = tile[tx][ty + j];
}

extern "C" void kernel_launch(void* const* d_in, const int* in_sizes, int n_in,
                              void* d_out, int out_size, void* d_ws, size_t ws_size,
                              hipStream_t stream) {
    const float* img = (const float*)d_in[0];
    const float* dp  = (const float*)d_in[1];
    const float* dv  = (const float*)d_in[2];
    const float* K   = (const float*)d_in[3];
    const float* T   = (const float*)d_in[4];
    float* out = (float*)d_out;

    _Float16* img_t = (_Float16*)d_ws;                  // WS_IMG_T == 0
    int*   tot    = (int*)d_ws + WS_TOT;
    int*   hist2  = (int*)d_ws + WS_HIST2;
    float* out_t  = (float*)d_ws + WS_OUT_T;
    int*   offs   = (int*)d_ws + WS_OFFS;
    int*   ekey   = (int*)d_ws + WS_EKEY;
    unsigned short* ew16 = (unsigned short*)((int*)d_ws + WS_EW16);
    (void)ws_size;

    // zero tot + hist2 (contiguous, ~2.1 MB); out_t zeroed inside k_prep
    hipMemsetAsync(tot, 0, MEMSET_WORDS * sizeof(int), stream);

    k_prep<<<PREP_TOTAL, 256, 0, stream>>>(img, img_t, dv, K, T, hist2,
                                           (float4*)out_t);
    k_scan<<<SCAN_BLOCKS, 256, 0, stream>>>(hist2, offs, tot);
    k_fill<<<NPTS / 256, 256, 0, stream>>>(dp, dv, K, T, offs, hist2, ekey, ew16);
    k_chunk_gather<<<GATHER_BLOCKS, 256, 0, stream>>>(img_t, offs, ekey, ew16, out_t);
    k_untranspose<<<dim3(NCELL / 32, C_DIM / 32, B_DIM), dim3(32, 8), 0, stream>>>(
        out_t, out);
}